// Round 16
// baseline (418.454 us; speedup 1.0000x reference)
//
#include <hip/hip_runtime.h>
#include <hip/hip_bf16.h>

#define NB 256
#define NL 64
#define DEG 6
#define FEAT 39
#define BOND 10
#define FP 256
#define NEGV (-9.0e8f)

using s16x8 = __attribute__((ext_vector_type(8))) short;
using f32x4 = __attribute__((ext_vector_type(4))) float;

__device__ __forceinline__ unsigned short f2bf(float f){
  unsigned u = __float_as_uint(f);
  u += 0x7fffu + ((u >> 16) & 1u);      // RNE
  return (unsigned short)(u >> 16);
}
__device__ __forceinline__ float lo16(unsigned u){ return __uint_as_float(u << 16); }
__device__ __forceinline__ float hi16(unsigned u){ return __uint_as_float(u & 0xffff0000u); }

__device__ __forceinline__ float block_sum256(float v, float* scr){
  #pragma unroll
  for(int o=32;o>0;o>>=1) v += __shfl_down(v, o, 64);
  __syncthreads();
  if((threadIdx.x & 63) == 0) scr[threadIdx.x >> 6] = v;
  __syncthreads();
  return scr[0] + scr[1] + scr[2] + scr[3];
}
__device__ __forceinline__ float wave_allsum(float v){
  #pragma unroll
  for(int o=1;o<64;o<<=1) v += __shfl_xor(v, o, 64);
  return v;
}

// ---------- sizes ----------
#define MCVT_N0 65536    // mol_attend_w
#define MCVT_N1 196608   // mg_wih
#define MCVT_N2 196608   // mg_whh
#define MCVT_TOT (MCVT_N0+MCVT_N1+MCVT_N2)          // 458,752
#define CTXPK_N (3*8*8192)                          // 196,608
#define GPK_N   (3*2*8*24576)                       // 1,179,648
#define HALF_U16 24576

// ---- mol-weight bf16 convert ----
__global__ void k_cvt_mol(const float* __restrict__ a0, const float* __restrict__ a1,
                          const float* __restrict__ a2, unsigned short* __restrict__ dst){
  int i = blockIdx.x*256 + threadIdx.x;
  if(i >= MCVT_TOT) return;
  int off = i; const float* src;
  if(off < MCVT_N0) src = a0;
  else { off -= MCVT_N0;
    if(off < MCVT_N1) src = a1;
    else { off -= MCVT_N1; src = a2; } }
  dst[i] = f2bf(src[off]);
}

// ---- k_pack: fragment-ordered bf16 weight images (round-9 verified layout) ----
__global__ void k_pack(const float* __restrict__ attend_w, const float* __restrict__ gru_wih,
                       const float* __restrict__ gru_whh,
                       unsigned short* __restrict__ ctx_pk, unsigned short* __restrict__ gates_pk){
  int i = blockIdx.x*256 + threadIdx.x;
  if(i < CTXPK_N){
    int d = i >> 16;
    int rem = i & 65535;
    int kk = rem >> 13;
    int r2 = rem & 8191;
    int g = r2 >> 9;
    int l = (r2 >> 3) & 63;
    int q = r2 & 7;
    int row = g*16 + (l & 15);
    int k = kk*32 + (l >> 4)*8 + q;
    ctx_pk[i] = f2bf(attend_w[((size_t)d*256 + row)*256 + k]);
  } else {
    int j = i - CTXPK_N;
    if(j >= GPK_N) return;
    int d = j / 393216;
    int rem = j - d*393216;
    int nc = rem / 196608; rem -= nc*196608;
    int kk = rem / 24576;  rem -= kk*24576;
    int f = rem >> 9;
    int l = (rem >> 3) & 63;
    int q = rem & 7;
    int s = f >> 3, g = f & 7;
    int row = nc*128 + g*16 + (l & 15);
    int k = kk*32 + (l >> 4)*8 + q;
    float v = (s < 3) ? gru_wih[(((size_t)d*3 + s)*256 + row)*256 + k]
                      : gru_whh[(((size_t)d*3 + (s-3))*256 + row)*256 + k];
    gates_pk[j] = f2bf(v);
  }
}

// ---- k_tr (round-6 verified) ----
__global__ void k_tr(const float* __restrict__ aw, const float* __restrict__ nw,
                     float* __restrict__ afcT, unsigned short* __restrict__ nfcT){
  int i = blockIdx.x*256 + threadIdx.x;
  if(i < 40*256){
    int k = i >> 8, r = i & 255;
    afcT[i] = (k < FEAT) ? aw[r*FEAT + k] : 0.f;
  } else {
    int j = i - 40*256;           // < 52*256
    int k = j >> 8, r = j & 255;
    nfcT[j] = (k < FEAT+BOND) ? f2bf(nw[r*(FEAT+BOND) + k]) : (unsigned short)0;
  }
}

// ---- K1: atom FC (round-11 verified, L2-direct weights) ----
__global__ __launch_bounds__(256) void k_atom4(const float* __restrict__ atom,
    const float* __restrict__ afcT, const float* __restrict__ bias, float* __restrict__ af){
  __shared__ float x_s[4][40];
  const int t = threadIdx.x, bl0 = blockIdx.x*4;
  for(int idx=t; idx<4*FEAT; idx+=256){ int a=idx/FEAT, k=idx%FEAT; x_s[a][k]=atom[(bl0+a)*FEAT+k]; }
  if(t < 4) x_s[t][39] = 0.f;
  __syncthreads();
  const int w = t>>6, t0 = (t&63)*4, row = bl0 + w;
  float4 b4 = *(const float4*)&bias[t0];
  float acc[4] = {b4.x, b4.y, b4.z, b4.w};
  for(int k=0;k<40;++k){
    float iv = x_s[w][k];
    float4 wv = *(const float4*)&afcT[(k<<8)+t0];
    acc[0]=fmaf(iv,wv.x,acc[0]); acc[1]=fmaf(iv,wv.y,acc[1]);
    acc[2]=fmaf(iv,wv.z,acc[2]); acc[3]=fmaf(iv,wv.w,acc[3]);
  }
  float4 o;
  o.x = acc[0]>0.f?acc[0]:0.01f*acc[0]; o.y = acc[1]>0.f?acc[1]:0.01f*acc[1];
  o.z = acc[2]>0.f?acc[2]:0.01f*acc[2]; o.w = acc[3]>0.f?acc[3]:0.01f*acc[3];
  *(float4*)&af[(size_t)row*FP + t0] = o;
}

// ---- K2: neighbor FC + align + softmax + weighted sum (round-11 verified) ----
__global__ __launch_bounds__(256) void k_nbr4(const float* __restrict__ atom,
    const float* __restrict__ bond, const int* __restrict__ adl, const int* __restrict__ bdl,
    const unsigned short* __restrict__ nfcT, const float* __restrict__ bn,
    const float* __restrict__ alw, const float* __restrict__ alb,
    const float* __restrict__ af, float* __restrict__ wnf, float* __restrict__ swb){
  __shared__ float in_s[4][DEG][52];
  __shared__ int   ai_s[4][DEG];
  const int t = threadIdx.x, bl0 = blockIdx.x*4;
  if(t < 24){ int a=t/6, d=t%6; ai_s[a][d] = adl[(bl0+a)*DEG + d]; }
  __syncthreads();
  for(int idx=t; idx<4*DEG*(FEAT+BOND); idx+=256){
    int a = idx/(DEG*(FEAT+BOND)), rem = idx%(DEG*(FEAT+BOND));
    int d = rem/(FEAT+BOND), k = rem%(FEAT+BOND);
    int bb = (bl0+a) >> 6;
    float v;
    if(k < FEAT) v = atom[((size_t)bb*NL + ai_s[a][d])*FEAT + k];
    else { int bi = bdl[(bl0+a)*DEG + d]; v = bond[((size_t)bb*NL + bi)*BOND + (k-FEAT)]; }
    in_s[a][d][k] = v;
  }
  if(t < 24){ int a=t/6, d=t%6; in_s[a][d][49]=0.f; in_s[a][d][50]=0.f; in_s[a][d][51]=0.f; }
  __syncthreads();
  const int w = t>>6, lane = t&63, t0 = lane*4, row = bl0 + w;
  float acc[DEG][4] = {};
  for(int k=0;k<52;++k){
    uint2 u = *(const uint2*)&nfcT[(k<<8) + t0];
    float w0=lo16(u.x), w1=hi16(u.x), w2=lo16(u.y), w3=hi16(u.y);
    #pragma unroll
    for(int d=0;d<DEG;++d){
      float iv = in_s[w][d][k];
      acc[d][0]=fmaf(iv,w0,acc[d][0]); acc[d][1]=fmaf(iv,w1,acc[d][1]);
      acc[d][2]=fmaf(iv,w2,acc[d][2]); acc[d][3]=fmaf(iv,w3,acc[d][3]);
    }
  }
  float4 bnv = *(const float4*)&bn[t0];
  float bna[4] = {bnv.x, bnv.y, bnv.z, bnv.w};
  float nf[DEG][4];
  #pragma unroll
  for(int d=0;d<DEG;++d)
    #pragma unroll
    for(int j=0;j<4;++j){ float v = acc[d][j] + bna[j]; nf[d][j] = v>0.f ? v : 0.01f*v; }
  float4 af4 = *(const float4*)&af[(size_t)row*FP + t0];
  float4 a1  = *(const float4*)&alw[t0];
  float4 a2  = *(const float4*)&alw[FP + t0];
  float sa = wave_allsum(af4.x*a1.x + af4.y*a1.y + af4.z*a1.z + af4.w*a1.w);
  float sd[DEG];
  #pragma unroll
  for(int d=0;d<DEG;++d)
    sd[d] = wave_allsum(nf[d][0]*a2.x + nf[d][1]*a2.y + nf[d][2]*a2.z + nf[d][3]*a2.w);
  float ab = alb[0];
  float sc[DEG], msk[DEG];
  #pragma unroll
  for(int d=0;d<DEG;++d){
    float v = sa + sd[d] + ab;
    v = v>0.f ? v : 0.01f*v;
    msk[d] = (ai_s[w][d] == NL-1) ? 0.f : 1.f;
    sc[d] = v + (msk[d] > 0.f ? 0.f : NEGV);
  }
  float m = sc[0];
  #pragma unroll
  for(int d=1;d<DEG;++d) m = fmaxf(m, sc[d]);
  float e[DEG], Z = 0.f;
  #pragma unroll
  for(int d=0;d<DEG;++d){ e[d] = expf(sc[d]-m); Z += e[d]; }
  float wgt[DEG], sw = 0.f;
  #pragma unroll
  for(int d=0;d<DEG;++d){ wgt[d] = e[d]/Z*msk[d]; sw += wgt[d]; }
  float o[4] = {};
  #pragma unroll
  for(int d=0;d<DEG;++d)
    #pragma unroll
    for(int j=0;j<4;++j) o[j] = fmaf(wgt[d], nf[d][j], o[j]);
  float4 ov; ov.x=o[0]; ov.y=o[1]; ov.z=o[2]; ov.w=o[3];
  *(float4*)&wnf[(size_t)row*FP + t0] = ov;
  if(lane == 0) swb[row] = sw;
}

// ======== K3 R16: fused 3-radius recurrence — 1024 threads (16 waves), grid/LDS unchanged ========
// 16 waves = wm(2 x 32 rows) x wn(8). Per-wave: ctx 2 n-frags; gates col-group g=wn.
// Pipeline/schedule/pack layouts identical to r12-verified; per-wave tiling halved.
__global__ __launch_bounds__(1024, 1) void k_radius7(
    const float* __restrict__ wnf, float* __restrict__ af, const float* __restrict__ swb,
    const unsigned short* __restrict__ ctx_pk, const unsigned short* __restrict__ gates_pk,
    const float* __restrict__ attend_b,
    const float* __restrict__ gru_bih, const float* __restrict__ gru_bhh){
  __shared__ __align__(16) unsigned short Cf[32*512];
  __shared__ __align__(16) unsigned short Bu[2][HALF_U16];
  const int t = threadIdx.x;
  const int w = t>>6, lane = t&63, lr = lane&15, ks = lane>>4;
  const int wm = w>>3, wn = w&7;
  const int m0 = blockIdx.x*64;

  s16x8 pf[3]; int pfn = 0;
  auto LOADS = [&](int s){
    if(s >= 72) return;
    int d2 = s/24, r = s - d2*24;
    const unsigned short* src; int n;
    if(r < 8){ n = 1; src = ctx_pk + ((size_t)d2*8 + r)*8192; }
    else { int g = r - 8; n = 3; src = gates_pk + ((size_t)(d2*2 + (g>>3))*8 + (g&7))*24576; }
    pfn = n;
    #pragma unroll
    for(int c=0;c<3;++c) if(c < n) pf[c] = *(const s16x8*)(src + (w + c*16)*512 + lane*8);
  };
  auto WRITET = [&](int h){
    #pragma unroll
    for(int c=0;c<3;++c) if(c < pfn) *(s16x8*)&Bu[h][(w + c*16)*512 + lane*8] = pf[c];
  };

  LOADS(0);
  WRITET(0);
  LOADS(1);
  int half = 0;

  for(int d=0; d<3; ++d){
    const float* bat  = attend_b + d*256;
    const float* bihd = gru_bih + d*768;
    const float* bhhd = gru_bhh + d*768;

    __syncthreads();      // order prior-radius GRU writes before x preload
    float4 px0[2], px1[2];
    #pragma unroll
    for(int mf=0; mf<2; ++mf){
      int row = m0 + wm*32 + mf*16 + lr;
      const float* sp = (d==0 ? wnf : af) + (size_t)row*256 + ks*8;
      px0[mf] = *(const float4*)sp; px1[mf] = *(const float4*)(sp+4);
    }
    // ---------------- phase 2: ctx (swapped-operand MFMA) ----------------
    f32x4 acc2[2][2] = {};
    for(int kk=0; kk<8; ++kk){
      int s = d*24 + kk;
      __syncthreads();
      WRITET(half^1);
      LOADS(s+2);
      float4 cx0[2] = {px0[0], px0[1]};
      float4 cx1[2] = {px1[0], px1[1]};
      if(kk < 7){
        #pragma unroll
        for(int mf=0; mf<2; ++mf){
          int row = m0 + wm*32 + mf*16 + lr;
          const float* sp = (d==0 ? wnf : af) + (size_t)row*256 + (kk+1)*32 + ks*8;
          px0[mf] = *(const float4*)sp; px1[mf] = *(const float4*)(sp+4);
        }
      }
      s16x8 xf[2];
      #pragma unroll
      for(int mf=0; mf<2; ++mf){
        float4 v0 = cx0[mf], v1 = cx1[mf];
        if(d != 0){
          float sw = swb[m0 + wm*32 + mf*16 + lr];
          v0.x=fmaxf(v0.x,0.f)*sw; v0.y=fmaxf(v0.y,0.f)*sw;
          v0.z=fmaxf(v0.z,0.f)*sw; v0.w=fmaxf(v0.w,0.f)*sw;
          v1.x=fmaxf(v1.x,0.f)*sw; v1.y=fmaxf(v1.y,0.f)*sw;
          v1.z=fmaxf(v1.z,0.f)*sw; v1.w=fmaxf(v1.w,0.f)*sw;
        }
        unsigned short tmp[8] = {f2bf(v0.x),f2bf(v0.y),f2bf(v0.z),f2bf(v0.w),
                                 f2bf(v1.x),f2bf(v1.y),f2bf(v1.z),f2bf(v1.w)};
        xf[mf] = *(s16x8*)tmp;
      }
      #pragma unroll
      for(int nf=0; nf<2; ++nf){
        s16x8 wf = *(const s16x8*)&Bu[half][((wn*2 + nf)*64 + lane)*8];
        acc2[0][nf] = __builtin_amdgcn_mfma_f32_16x16x32_bf16(wf, xf[0], acc2[0][nf],0,0,0);
        acc2[1][nf] = __builtin_amdgcn_mfma_f32_16x16x32_bf16(wf, xf[1], acc2[1][nf],0,0,0);
      }
      half ^= 1;
    }
    // ctx epilogue -> Cf (gf-uniform addr formula, r9-verified)
    #pragma unroll
    for(int mf=0; mf<2; ++mf){
      float swv = swb[m0 + wm*32 + mf*16 + lr];
      #pragma unroll
      for(int nf=0; nf<2; ++nf){
        int gf = wn*2 + nf;                    // global n-frag 0..15
        int nb = gf*16 + ks*4;
        float4 b4 = *(const float4*)&bat[nb];
        float bj[4] = {b4.x, b4.y, b4.z, b4.w};
        unsigned short o4[4];
        #pragma unroll
        for(int j=0;j<4;++j){
          float v = acc2[mf][nf][j] + swv*bj[j];
          v = v > 0.f ? v : expm1f(v);
          o4[j] = f2bf(v);
        }
        int gm = wm*2 + mf;
        int kkp = gf >> 1;
        int lhi = ((gf & 1) << 1) | (ks >> 1);
        int addr = (gm*8 + kkp)*512 + (lhi*16 + lr)*8 + (ks & 1)*4;
        *(uint2*)&Cf[addr] = *(uint2*)o4;
      }
    }
    // ---- preload h frags for (nc=0, kk=0) ----
    float4 ph0[2], ph1[2];
    #pragma unroll
    for(int mf=0; mf<2; ++mf){
      int row = m0 + wm*32 + mf*16 + lr;
      const float* sp = af + (size_t)row*256 + ks*8;
      ph0[mf] = *(const float4*)sp; ph1[mf] = *(const float4*)(sp+4);
    }
    // ---------------- phase 3: gates + GRU (col-group g=wn; deferred nc=0 writes) ----------------
    float hnew0[2][4];
    for(int nc=0; nc<2; ++nc){
      f32x4 aR[2] = {}, aZ[2] = {}, aN[2] = {}, aH[2] = {};
      for(int kk=0; kk<8; ++kk){
        int s = d*24 + 8 + nc*8 + kk;
        __syncthreads();
        if(s < 71) WRITET(half^1);
        LOADS(s+2);
        float4 ch0[2] = {ph0[0], ph0[1]};
        float4 ch1[2] = {ph1[0], ph1[1]};
        bool lastHK = (nc == 1) && (kk == 7);
        if(!lastHK){
          int kkn = (kk < 7) ? kk+1 : 0;
          #pragma unroll
          for(int mf=0; mf<2; ++mf){
            int row = m0 + wm*32 + mf*16 + lr;
            const float* sp = af + (size_t)row*256 + kkn*32 + ks*8;
            ph0[mf] = *(const float4*)sp; ph1[mf] = *(const float4*)(sp+4);
          }
        }
        s16x8 hf[2];
        #pragma unroll
        for(int mf=0; mf<2; ++mf){
          float4 v0 = ch0[mf], v1 = ch1[mf];
          unsigned short tmp[8] = {f2bf(v0.x),f2bf(v0.y),f2bf(v0.z),f2bf(v0.w),
                                   f2bf(v1.x),f2bf(v1.y),f2bf(v1.z),f2bf(v1.w)};
          hf[mf] = *(s16x8*)tmp;
        }
        s16x8 cf0 = *(const s16x8*)&Cf[((wm*2 + 0)*8 + kk)*512 + lane*8];
        s16x8 cf1 = *(const s16x8*)&Cf[((wm*2 + 1)*8 + kk)*512 + lane*8];
        {
          int g = wn;
          s16x8 b0 = *(const s16x8*)&Bu[half][((0*8 + g)*64 + lane)*8];
          s16x8 b1 = *(const s16x8*)&Bu[half][((1*8 + g)*64 + lane)*8];
          s16x8 b2 = *(const s16x8*)&Bu[half][((2*8 + g)*64 + lane)*8];
          s16x8 b3 = *(const s16x8*)&Bu[half][((3*8 + g)*64 + lane)*8];
          s16x8 b4 = *(const s16x8*)&Bu[half][((4*8 + g)*64 + lane)*8];
          s16x8 b5 = *(const s16x8*)&Bu[half][((5*8 + g)*64 + lane)*8];
          aR[0] = __builtin_amdgcn_mfma_f32_16x16x32_bf16(cf0, b0, aR[0],0,0,0);
          aR[1] = __builtin_amdgcn_mfma_f32_16x16x32_bf16(cf1, b0, aR[1],0,0,0);
          aZ[0] = __builtin_amdgcn_mfma_f32_16x16x32_bf16(cf0, b1, aZ[0],0,0,0);
          aZ[1] = __builtin_amdgcn_mfma_f32_16x16x32_bf16(cf1, b1, aZ[1],0,0,0);
          aN[0] = __builtin_amdgcn_mfma_f32_16x16x32_bf16(cf0, b2, aN[0],0,0,0);
          aN[1] = __builtin_amdgcn_mfma_f32_16x16x32_bf16(cf1, b2, aN[1],0,0,0);
          aR[0] = __builtin_amdgcn_mfma_f32_16x16x32_bf16(hf[0], b3, aR[0],0,0,0);
          aR[1] = __builtin_amdgcn_mfma_f32_16x16x32_bf16(hf[1], b3, aR[1],0,0,0);
          aZ[0] = __builtin_amdgcn_mfma_f32_16x16x32_bf16(hf[0], b4, aZ[0],0,0,0);
          aZ[1] = __builtin_amdgcn_mfma_f32_16x16x32_bf16(hf[1], b4, aZ[1],0,0,0);
          aH[0] = __builtin_amdgcn_mfma_f32_16x16x32_bf16(hf[0], b5, aH[0],0,0,0);
          aH[1] = __builtin_amdgcn_mfma_f32_16x16x32_bf16(hf[1], b5, aH[1],0,0,0);
        }
        half ^= 1;
      }
      if(nc == 0){
        #pragma unroll
        for(int mf=0; mf<2; ++mf){
          int n = wn*16 + lr;
          float brz = bihd[n] + bhhd[n];
          float bzz = bihd[256+n] + bhhd[256+n];
          float bnn = bihd[512+n];
          float bhn = bhhd[512+n];
          #pragma unroll
          for(int j=0;j<4;++j){
            int m = m0 + wm*32 + mf*16 + ks*4 + j;
            float hold = af[(size_t)m*256 + n];
            float r = 1.f/(1.f + expf(-(aR[mf][j] + brz)));
            float z = 1.f/(1.f + expf(-(aZ[mf][j] + bzz)));
            float ng = tanhf(aN[mf][j] + bnn + r*(aH[mf][j] + bhn));
            hnew0[mf][j] = (1.f - z)*ng + z*hold;
          }
        }
      } else {
        #pragma unroll
        for(int mf=0; mf<2; ++mf){
          int n = 128 + wn*16 + lr;
          float brz = bihd[n] + bhhd[n];
          float bzz = bihd[256+n] + bhhd[256+n];
          float bnn = bihd[512+n];
          float bhn = bhhd[512+n];
          #pragma unroll
          for(int j=0;j<4;++j){
            int m = m0 + wm*32 + mf*16 + ks*4 + j;
            float hold = af[(size_t)m*256 + n];
            float r = 1.f/(1.f + expf(-(aR[mf][j] + brz)));
            float z = 1.f/(1.f + expf(-(aZ[mf][j] + bzz)));
            float ng = tanhf(aN[mf][j] + bnn + r*(aH[mf][j] + bhn));
            af[(size_t)m*256 + n] = (1.f - z)*ng + z*hold;
          }
        }
        #pragma unroll
        for(int mf=0; mf<2; ++mf){
          int n = wn*16 + lr;
          #pragma unroll
          for(int j=0;j<4;++j){
            int m = m0 + wm*32 + mf*16 + ks*4 + j;
            af[(size_t)m*256 + n] = hnew0[mf][j];
          }
        }
      }
    }
  }
}

// ======== K4a — att = X @ W^T + b (f32 out, MFMA) ========
__global__ __launch_bounds__(256) void k_lin_gemm(
    const float* __restrict__ Xsrc, const unsigned short* __restrict__ Wbf,
    const float* __restrict__ bias, float* __restrict__ Y){
  __shared__ unsigned short A_lds[64][264];
  __shared__ unsigned short B_lds[64][264];
  const int t = threadIdx.x;
  const int m0 = (blockIdx.x >> 2) * 64, n0 = (blockIdx.x & 3) * 64;
  const int rb = t >> 4, cb = (t & 15) * 16;
  for(int i=0;i<4;++i){
    int row = i*16 + rb;
    const float* src = Xsrc + (size_t)(m0+row)*FP + cb;
    unsigned short tmp[16];
    #pragma unroll
    for(int q=0;q<4;++q){
      float4 v = ((const float4*)src)[q];
      tmp[q*4+0]=f2bf(v.x); tmp[q*4+1]=f2bf(v.y); tmp[q*4+2]=f2bf(v.z); tmp[q*4+3]=f2bf(v.w);
    }
    *(s16x8*)&A_lds[row][cb]   = *(s16x8*)&tmp[0];
    *(s16x8*)&A_lds[row][cb+8] = *(s16x8*)&tmp[8];
    const unsigned short* wsrc = Wbf + (size_t)(n0+row)*FP + cb;
    *(s16x8*)&B_lds[row][cb]   = *(const s16x8*)&wsrc[0];
    *(s16x8*)&B_lds[row][cb+8] = *(const s16x8*)&wsrc[8];
  }
  __syncthreads();
  const int w = t>>6, lane = t&63, lr = lane&15, ks = lane>>4;
  const int wr = (w>>1)*32, wc = (w&1)*32;
  f32x4 acc[2][2] = {};
  #pragma unroll
  for(int kk=0;kk<8;++kk){
    int ko = kk*32 + ks*8;
    s16x8 a0 = *(const s16x8*)&A_lds[wr+lr][ko];
    s16x8 a1 = *(const s16x8*)&A_lds[wr+16+lr][ko];
    s16x8 b0 = *(const s16x8*)&B_lds[wc+lr][ko];
    s16x8 b1 = *(const s16x8*)&B_lds[wc+16+lr][ko];
    acc[0][0] = __builtin_amdgcn_mfma_f32_16x16x32_bf16(a0,b0,acc[0][0],0,0,0);
    acc[0][1] = __builtin_amdgcn_mfma_f32_16x16x32_bf16(a0,b1,acc[0][1],0,0,0);
    acc[1][0] = __builtin_amdgcn_mfma_f32_16x16x32_bf16(a1,b0,acc[1][0],0,0,0);
    acc[1][1] = __builtin_amdgcn_mfma_f32_16x16x32_bf16(a1,b1,acc[1][1],0,0,0);
  }
  #pragma unroll
  for(int fm=0;fm<2;++fm)
    #pragma unroll
    for(int fn=0;fn<2;++fn){
      int n = n0 + wc + fn*16 + lr;
      float bv = bias[n];
      #pragma unroll
      for(int j=0;j<4;++j){
        int m = m0 + wr + fm*16 + ks*4 + j;
        Y[(size_t)m*FP + n] = acc[fm][fn][j] + bv;
      }
    }
}

// ======== K3b (mol) — 6 gate GEMMs + fused GRU, 32-row tiles ========
__global__ __launch_bounds__(256) void k_gates32(
    const unsigned short* __restrict__ ctxbf, const float* __restrict__ h_glob,
    const unsigned short* __restrict__ wihbf, const unsigned short* __restrict__ whhbf,
    const float* __restrict__ bih, const float* __restrict__ bhh,
    float* __restrict__ h_out){
  __shared__ unsigned short A_ctx[32][40];
  __shared__ unsigned short A_h[32][40];
  __shared__ unsigned short B_lds[6][64][40];
  const int t = threadIdx.x;
  const int m0 = (blockIdx.x >> 2) * 32, nc = (blockIdx.x & 3) * 64;
  const int w = t>>6, lane = t&63, lr = lane&15, ks = lane>>4;
  const int mh = (w>>1)*16, nh = (w&1)*32;
  f32x4 acc[6][2] = {};
  for(int kk=0;kk<8;++kk){
    const int k0 = kk*32;
    __syncthreads();
    {
      int row = t>>3, c4 = (t&7)*4;
      *(uint2*)&A_ctx[row][c4] = *(const uint2*)(ctxbf + (size_t)(m0+row)*FP + k0 + c4);
      float4 hv = *(const float4*)(h_glob + (size_t)(m0+row)*FP + k0 + c4);
      unsigned short ht[4] = {f2bf(hv.x), f2bf(hv.y), f2bf(hv.z), f2bf(hv.w)};
      *(uint2*)&A_h[row][c4] = *(uint2*)ht;
    }
    #pragma unroll
    for(int i=0;i<6;++i){
      int idx = i*256 + t;
      int s = idx >> 8, rem = idx & 255;
      int row = rem >> 2, c8 = (rem & 3)*8;
      const unsigned short* wsrc = (s < 3)
          ? wihbf + (size_t)(s*FP + nc + row)*FP + k0 + c8
          : whhbf + (size_t)((s-3)*FP + nc + row)*FP + k0 + c8;
      *(s16x8*)&B_lds[s][row][c8] = *(const s16x8*)wsrc;
    }
    __syncthreads();
    s16x8 ac = *(const s16x8*)&A_ctx[mh+lr][ks*8];
    s16x8 ah = *(const s16x8*)&A_h[mh+lr][ks*8];
    #pragma unroll
    for(int s=0;s<6;++s){
      s16x8 a = (s < 3) ? ac : ah;
      #pragma unroll
      for(int fn=0;fn<2;++fn){
        s16x8 b = *(const s16x8*)&B_lds[s][nh+fn*16+lr][ks*8];
        acc[s][fn] = __builtin_amdgcn_mfma_f32_16x16x32_bf16(a,b,acc[s][fn],0,0,0);
      }
    }
  }
  #pragma unroll
  for(int fn=0;fn<2;++fn){
    int n = nc + nh + fn*16 + lr;
    float bir = bih[n], biz = bih[FP+n], bin_ = bih[2*FP+n];
    float bhr = bhh[n], bhz = bhh[FP+n], bhn  = bhh[2*FP+n];
    #pragma unroll
    for(int j=0;j<4;++j){
      int m = m0 + mh + ks*4 + j;
      float h = h_glob[(size_t)m*FP + n];
      float ir = acc[0][fn][j]+bir, iz = acc[1][fn][j]+biz, inn = acc[2][fn][j]+bin_;
      float hr = acc[3][fn][j]+bhr, hz = acc[4][fn][j]+bhz, hn  = acc[5][fn][j]+bhn;
      float r = 1.f/(1.f + expf(-(ir+hr)));
      float z = 1.f/(1.f + expf(-(iz+hz)));
      float ng = tanhf(inn + r*hn);
      h_out[(size_t)m*FP + n] = (1.f-z)*ng + z*h;
    }
  }
}

// ======== K4b — molfeat = sum relu(af)*mask; emit out_af ========
__global__ void k_finalize(const float* __restrict__ af, const float* __restrict__ mask,
                           float* __restrict__ molfeat, float* __restrict__ out_af){
  const int b = blockIdx.x, t = threadIdx.x;
  __shared__ float msk_s[NL];
  if(t < NL) msk_s[t] = mask[b*NL + t];
  __syncthreads();
  float mf = 0.f;
  for(int l=0;l<NL;++l){
    float v = af[(size_t)(b*NL + l)*FP + t];
    out_af[(size_t)(b*NL + l)*FP + t] = v;
    mf = fmaf(fmaxf(v,0.f), msk_s[l], mf);
  }
  molfeat[b*FP + t] = mf;
}

// ======== K5a — mol attention -> ctx (bf16) ========
__global__ void k_mol_ctx(const float* __restrict__ af, const float* __restrict__ att,
    const float* __restrict__ mfin, const float* __restrict__ maw,
    const float* __restrict__ mabp, const float* __restrict__ mask,
    unsigned short* __restrict__ ctxb){
  const int b = blockIdx.x, t = threadIdx.x;
  __shared__ float mf_s[FP];
  __shared__ float sc_s[NL], aw_s[NL], scr[4];
  mf_s[t] = mfin[b*FP + t];
  __syncthreads();
  float sa = block_sum256(maw[t]*mf_s[t], scr);
  int l = t >> 2, q = t & 3;
  float p = 0.f;
  {
    const float4* ar = (const float4*)(af + (size_t)(b*NL + l)*FP + q*64);
    const float4* w2 = (const float4*)(maw + FP + q*64);
    #pragma unroll
    for(int k=0;k<16;++k){
      float4 a = ar[k], ww = w2[k];
      p = fmaf(a.x,ww.x,p); p = fmaf(a.y,ww.y,p);
      p = fmaf(a.z,ww.z,p); p = fmaf(a.w,ww.w,p);
    }
  }
  p += __shfl_xor(p, 1, 64);
  p += __shfl_xor(p, 2, 64);
  if(q == 0){
    float mv = mask[b*NL + l];
    float v = sa + p + mabp[0];
    v = v > 0.f ? v : 0.01f*v;
    sc_s[l] = v + (mv == 0.f ? NEGV : 0.f);
  }
  __syncthreads();
  if(t < NL){
    float s = sc_s[t];
    float m = s;
    #pragma unroll
    for(int o=32;o>0;o>>=1) m = fmaxf(m, __shfl_xor(m, o, 64));
    float e = expf(s - m);
    float Z = e;
    #pragma unroll
    for(int o=32;o>0;o>>=1) Z += __shfl_xor(Z, o, 64);
    aw_s[t] = e / Z * mask[b*NL + t];
  }
  __syncthreads();
  float acc = 0.f;
  for(int l2=0;l2<NL;++l2) acc = fmaf(aw_s[l2], att[(size_t)(b*NL + l2)*FP + t], acc);
  float c = acc > 0.f ? acc : expm1f(acc);
  ctxb[b*FP + t] = f2bf(c);
}

// ======== K6: mol_prediction ========
__global__ void k_out(const float* __restrict__ molfeat, const float* __restrict__ ow,
                      const float* __restrict__ ob, float* __restrict__ outp){
  const int b = blockIdx.x, t = threadIdx.x;
  __shared__ float scr[4];
  float s = block_sum256(molfeat[b*FP + t]*ow[t], scr);
  if(t == 0) outp[b] = s + ob[0];
}

extern "C" void kernel_launch(void* const* d_in, const int* in_sizes, int n_in,
                              void* d_out, int out_size, void* d_ws, size_t ws_size,
                              hipStream_t stream){
  const float* atom_list = (const float*)d_in[0];
  const float* bond_list = (const float*)d_in[1];
  const int*   adl       = (const int*)d_in[2];
  const int*   bdl       = (const int*)d_in[3];
  const float* amask     = (const float*)d_in[4];
  const float* afc_w     = (const float*)d_in[5];
  const float* afc_b     = (const float*)d_in[6];
  const float* nfc_w     = (const float*)d_in[7];
  const float* nfc_b     = (const float*)d_in[8];
  const float* align_w   = (const float*)d_in[9];
  const float* align_b   = (const float*)d_in[10];
  const float* attend_w  = (const float*)d_in[11];
  const float* attend_b  = (const float*)d_in[12];
  const float* gru_wih   = (const float*)d_in[13];
  const float* gru_whh   = (const float*)d_in[14];
  const float* gru_bih   = (const float*)d_in[15];
  const float* gru_bhh   = (const float*)d_in[16];
  const float* mol_align_w  = (const float*)d_in[17];
  const float* mol_align_b  = (const float*)d_in[18];
  const float* mol_attend_w = (const float*)d_in[19];
  const float* mol_attend_b = (const float*)d_in[20];
  const float* mg_wih    = (const float*)d_in[21];
  const float* mg_whh    = (const float*)d_in[22];
  const float* mg_bih    = (const float*)d_in[23];
  const float* mg_bhh    = (const float*)d_in[24];
  const float* out_w     = (const float*)d_in[25];
  const float* out_b     = (const float*)d_in[26];

  float* out_af   = (float*)d_out;
  float* out_pred = out_af + (size_t)NB*NL*FP;

  const size_t NROW = (size_t)NB*NL;          // 16384
  const size_t F32_CNT = 2*NROW*FP + NROW + 2*(size_t)NB*FP + 40*256;
  const size_t U16_CNT = (size_t)NB*FP + MCVT_TOT + 52*256 + CTXPK_N + GPK_N;
  const size_t NEED = F32_CNT*4 + U16_CNT*2;

  if(ws_size >= NEED){
    float* af_a    = (float*)d_ws;
    float* wnf     = af_a + NROW*FP;
    float* swb     = wnf  + NROW*FP;
    float* mf_a    = swb  + NROW;
    float* mf_b    = mf_a + (size_t)NB*FP;
    float* afcT    = mf_b + (size_t)NB*FP;
    unsigned short* ctxbf_m = (unsigned short*)(afcT + 40*256);   // mol ctx [NB][FP]
    unsigned short* maw_bf  = ctxbf_m + (size_t)NB*FP;
    unsigned short* mgih_bf = maw_bf + MCVT_N0;
    unsigned short* mghh_bf = mgih_bf + MCVT_N1;
    unsigned short* nfcT_bf = mghh_bf + MCVT_N2;
    unsigned short* ctx_pk  = nfcT_bf + 52*256;
    unsigned short* gates_pk= ctx_pk + CTXPK_N;

    k_cvt_mol<<<(MCVT_TOT+255)/256, 256, 0, stream>>>(mol_attend_w, mg_wih, mg_whh, maw_bf);
    k_pack<<<(CTXPK_N+GPK_N)/256, 256, 0, stream>>>(attend_w, gru_wih, gru_whh, ctx_pk, gates_pk);
    k_tr<<<(40*256 + 52*256)/256, 256, 0, stream>>>(afc_w, nfc_w, afcT, nfcT_bf);

    k_atom4<<<NB*NL/4, 256, 0, stream>>>(atom_list, afcT, afc_b, af_a);
    k_nbr4<<<NB*NL/4, 256, 0, stream>>>(atom_list, bond_list, adl, bdl,
                                        nfcT_bf, nfc_b, align_w, align_b, af_a, wnf, swb);
    k_radius7<<<NB*NL/64, 1024, 0, stream>>>(wnf, af_a, swb, ctx_pk, gates_pk,
                                             attend_b, gru_bih, gru_bhh);
    // mol phase
    k_lin_gemm<<<(NB*NL/64)*4, 256, 0, stream>>>(af_a, maw_bf, mol_attend_b, wnf);
    k_finalize<<<NB, 256, 0, stream>>>(af_a, amask, mf_a, out_af);
    float* m_cur = mf_a; float* m_nxt = mf_b;
    for(int s=0; s<2; ++s){
      k_mol_ctx<<<NB, 256, 0, stream>>>(af_a, wnf, m_cur, mol_align_w, mol_align_b,
                                        amask, ctxbf_m);
      k_gates32<<<(NB/32)*4, 256, 0, stream>>>(ctxbf_m, m_cur, mgih_bf, mghh_bf,
                                               mg_bih, mg_bhh, m_nxt);
      float* tmp = m_cur; m_cur = m_nxt; m_nxt = tmp;
    }
    k_out<<<NB, 256, 0, stream>>>(m_cur, out_w, out_b, out_pred);
  } else {
    // safety net (never taken with provided workspace)
    float* af = (float*)d_ws;
    k_atom4<<<NB*NL/4, 256, 0, stream>>>(atom_list, (const float*)afc_w, afc_b, af);
    (void)bond_list; (void)adl; (void)bdl; (void)amask;
    (void)align_w; (void)align_b; (void)attend_w; (void)attend_b;
    (void)gru_wih; (void)gru_whh; (void)gru_bih; (void)gru_bhh;
    (void)mol_align_w; (void)mol_align_b; (void)mol_attend_w; (void)mol_attend_b;
    (void)mg_wih; (void)mg_whh; (void)mg_bih; (void)mg_bhh; (void)out_w; (void)out_b;
  }
}

// Round 17
// 321.700 us; speedup vs baseline: 1.3008x; 1.3008x over previous
//
#include <hip/hip_runtime.h>
#include <hip/hip_bf16.h>

#define NB 256
#define NL 64
#define DEG 6
#define FEAT 39
#define BOND 10
#define FP 256
#define NEGV (-9.0e8f)

using s16x8 = __attribute__((ext_vector_type(8))) short;
using f32x4 = __attribute__((ext_vector_type(4))) float;

__device__ __forceinline__ unsigned short f2bf(float f){
  unsigned u = __float_as_uint(f);
  u += 0x7fffu + ((u >> 16) & 1u);      // RNE
  return (unsigned short)(u >> 16);
}
__device__ __forceinline__ float lo16(unsigned u){ return __uint_as_float(u << 16); }
__device__ __forceinline__ float hi16(unsigned u){ return __uint_as_float(u & 0xffff0000u); }

__device__ __forceinline__ float block_sum256(float v, float* scr){
  #pragma unroll
  for(int o=32;o>0;o>>=1) v += __shfl_down(v, o, 64);
  __syncthreads();
  if((threadIdx.x & 63) == 0) scr[threadIdx.x >> 6] = v;
  __syncthreads();
  return scr[0] + scr[1] + scr[2] + scr[3];
}
__device__ __forceinline__ float wave_allsum(float v){
  #pragma unroll
  for(int o=1;o<64;o<<=1) v += __shfl_xor(v, o, 64);
  return v;
}

// ---------- sizes ----------
#define MCVT_N0 65536    // mol_attend_w
#define MCVT_N1 196608   // mg_wih
#define MCVT_N2 196608   // mg_whh
#define MCVT_TOT (MCVT_N0+MCVT_N1+MCVT_N2)          // 458,752
#define CTXPK_N (3*8*8192)                          // 196,608
#define GPK_N   (3*2*8*24576)                       // 1,179,648
#define HALF_U16 24576

// ---- mol-weight bf16 convert ----
__global__ void k_cvt_mol(const float* __restrict__ a0, const float* __restrict__ a1,
                          const float* __restrict__ a2, unsigned short* __restrict__ dst){
  int i = blockIdx.x*256 + threadIdx.x;
  if(i >= MCVT_TOT) return;
  int off = i; const float* src;
  if(off < MCVT_N0) src = a0;
  else { off -= MCVT_N0;
    if(off < MCVT_N1) src = a1;
    else { off -= MCVT_N1; src = a2; } }
  dst[i] = f2bf(src[off]);
}

// ---- k_pack: fragment-ordered bf16 weight images (round-9 verified layout) ----
__global__ void k_pack(const float* __restrict__ attend_w, const float* __restrict__ gru_wih,
                       const float* __restrict__ gru_whh,
                       unsigned short* __restrict__ ctx_pk, unsigned short* __restrict__ gates_pk){
  int i = blockIdx.x*256 + threadIdx.x;
  if(i < CTXPK_N){
    int d = i >> 16;
    int rem = i & 65535;
    int kk = rem >> 13;
    int r2 = rem & 8191;
    int g = r2 >> 9;
    int l = (r2 >> 3) & 63;
    int q = r2 & 7;
    int row = g*16 + (l & 15);
    int k = kk*32 + (l >> 4)*8 + q;
    ctx_pk[i] = f2bf(attend_w[((size_t)d*256 + row)*256 + k]);
  } else {
    int j = i - CTXPK_N;
    if(j >= GPK_N) return;
    int d = j / 393216;
    int rem = j - d*393216;
    int nc = rem / 196608; rem -= nc*196608;
    int kk = rem / 24576;  rem -= kk*24576;
    int f = rem >> 9;
    int l = (rem >> 3) & 63;
    int q = rem & 7;
    int s = f >> 3, g = f & 7;
    int row = nc*128 + g*16 + (l & 15);
    int k = kk*32 + (l >> 4)*8 + q;
    float v = (s < 3) ? gru_wih[(((size_t)d*3 + s)*256 + row)*256 + k]
                      : gru_whh[(((size_t)d*3 + (s-3))*256 + row)*256 + k];
    gates_pk[j] = f2bf(v);
  }
}

// ---- k_tr (round-6 verified) ----
__global__ void k_tr(const float* __restrict__ aw, const float* __restrict__ nw,
                     float* __restrict__ afcT, unsigned short* __restrict__ nfcT){
  int i = blockIdx.x*256 + threadIdx.x;
  if(i < 40*256){
    int k = i >> 8, r = i & 255;
    afcT[i] = (k < FEAT) ? aw[r*FEAT + k] : 0.f;
  } else {
    int j = i - 40*256;           // < 52*256
    int k = j >> 8, r = j & 255;
    nfcT[j] = (k < FEAT+BOND) ? f2bf(nw[r*(FEAT+BOND) + k]) : (unsigned short)0;
  }
}

// ---- K1: atom FC (round-11 verified, L2-direct weights) ----
__global__ __launch_bounds__(256) void k_atom4(const float* __restrict__ atom,
    const float* __restrict__ afcT, const float* __restrict__ bias, float* __restrict__ af){
  __shared__ float x_s[4][40];
  const int t = threadIdx.x, bl0 = blockIdx.x*4;
  for(int idx=t; idx<4*FEAT; idx+=256){ int a=idx/FEAT, k=idx%FEAT; x_s[a][k]=atom[(bl0+a)*FEAT+k]; }
  if(t < 4) x_s[t][39] = 0.f;
  __syncthreads();
  const int w = t>>6, t0 = (t&63)*4, row = bl0 + w;
  float4 b4 = *(const float4*)&bias[t0];
  float acc[4] = {b4.x, b4.y, b4.z, b4.w};
  for(int k=0;k<40;++k){
    float iv = x_s[w][k];
    float4 wv = *(const float4*)&afcT[(k<<8)+t0];
    acc[0]=fmaf(iv,wv.x,acc[0]); acc[1]=fmaf(iv,wv.y,acc[1]);
    acc[2]=fmaf(iv,wv.z,acc[2]); acc[3]=fmaf(iv,wv.w,acc[3]);
  }
  float4 o;
  o.x = acc[0]>0.f?acc[0]:0.01f*acc[0]; o.y = acc[1]>0.f?acc[1]:0.01f*acc[1];
  o.z = acc[2]>0.f?acc[2]:0.01f*acc[2]; o.w = acc[3]>0.f?acc[3]:0.01f*acc[3];
  *(float4*)&af[(size_t)row*FP + t0] = o;
}

// ---- K2: neighbor FC + align + softmax + weighted sum (round-11 verified) ----
__global__ __launch_bounds__(256) void k_nbr4(const float* __restrict__ atom,
    const float* __restrict__ bond, const int* __restrict__ adl, const int* __restrict__ bdl,
    const unsigned short* __restrict__ nfcT, const float* __restrict__ bn,
    const float* __restrict__ alw, const float* __restrict__ alb,
    const float* __restrict__ af, float* __restrict__ wnf, float* __restrict__ swb){
  __shared__ float in_s[4][DEG][52];
  __shared__ int   ai_s[4][DEG];
  const int t = threadIdx.x, bl0 = blockIdx.x*4;
  if(t < 24){ int a=t/6, d=t%6; ai_s[a][d] = adl[(bl0+a)*DEG + d]; }
  __syncthreads();
  for(int idx=t; idx<4*DEG*(FEAT+BOND); idx+=256){
    int a = idx/(DEG*(FEAT+BOND)), rem = idx%(DEG*(FEAT+BOND));
    int d = rem/(FEAT+BOND), k = rem%(FEAT+BOND);
    int bb = (bl0+a) >> 6;
    float v;
    if(k < FEAT) v = atom[((size_t)bb*NL + ai_s[a][d])*FEAT + k];
    else { int bi = bdl[(bl0+a)*DEG + d]; v = bond[((size_t)bb*NL + bi)*BOND + (k-FEAT)]; }
    in_s[a][d][k] = v;
  }
  if(t < 24){ int a=t/6, d=t%6; in_s[a][d][49]=0.f; in_s[a][d][50]=0.f; in_s[a][d][51]=0.f; }
  __syncthreads();
  const int w = t>>6, lane = t&63, t0 = lane*4, row = bl0 + w;
  float acc[DEG][4] = {};
  for(int k=0;k<52;++k){
    uint2 u = *(const uint2*)&nfcT[(k<<8) + t0];
    float w0=lo16(u.x), w1=hi16(u.x), w2=lo16(u.y), w3=hi16(u.y);
    #pragma unroll
    for(int d=0;d<DEG;++d){
      float iv = in_s[w][d][k];
      acc[d][0]=fmaf(iv,w0,acc[d][0]); acc[d][1]=fmaf(iv,w1,acc[d][1]);
      acc[d][2]=fmaf(iv,w2,acc[d][2]); acc[d][3]=fmaf(iv,w3,acc[d][3]);
    }
  }
  float4 bnv = *(const float4*)&bn[t0];
  float bna[4] = {bnv.x, bnv.y, bnv.z, bnv.w};
  float nf[DEG][4];
  #pragma unroll
  for(int d=0;d<DEG;++d)
    #pragma unroll
    for(int j=0;j<4;++j){ float v = acc[d][j] + bna[j]; nf[d][j] = v>0.f ? v : 0.01f*v; }
  float4 af4 = *(const float4*)&af[(size_t)row*FP + t0];
  float4 a1  = *(const float4*)&alw[t0];
  float4 a2  = *(const float4*)&alw[FP + t0];
  float sa = wave_allsum(af4.x*a1.x + af4.y*a1.y + af4.z*a1.z + af4.w*a1.w);
  float sd[DEG];
  #pragma unroll
  for(int d=0;d<DEG;++d)
    sd[d] = wave_allsum(nf[d][0]*a2.x + nf[d][1]*a2.y + nf[d][2]*a2.z + nf[d][3]*a2.w);
  float ab = alb[0];
  float sc[DEG], msk[DEG];
  #pragma unroll
  for(int d=0;d<DEG;++d){
    float v = sa + sd[d] + ab;
    v = v>0.f ? v : 0.01f*v;
    msk[d] = (ai_s[w][d] == NL-1) ? 0.f : 1.f;
    sc[d] = v + (msk[d] > 0.f ? 0.f : NEGV);
  }
  float m = sc[0];
  #pragma unroll
  for(int d=1;d<DEG;++d) m = fmaxf(m, sc[d]);
  float e[DEG], Z = 0.f;
  #pragma unroll
  for(int d=0;d<DEG;++d){ e[d] = expf(sc[d]-m); Z += e[d]; }
  float wgt[DEG], sw = 0.f;
  #pragma unroll
  for(int d=0;d<DEG;++d){ wgt[d] = e[d]/Z*msk[d]; sw += wgt[d]; }
  float o[4] = {};
  #pragma unroll
  for(int d=0;d<DEG;++d)
    #pragma unroll
    for(int j=0;j<4;++j) o[j] = fmaf(wgt[d], nf[d][j], o[j]);
  float4 ov; ov.x=o[0]; ov.y=o[1]; ov.z=o[2]; ov.w=o[3];
  *(float4*)&wnf[(size_t)row*FP + t0] = ov;
  if(lane == 0) swb[row] = sw;
}

// ======== K3: fused 3-radius recurrence — r12 verified (2-deep weight pipeline + prefetch) ========
__global__ __launch_bounds__(512) void k_radius2(
    const float* __restrict__ wnf, float* __restrict__ af, const float* __restrict__ swb,
    const unsigned short* __restrict__ ctx_pk, const unsigned short* __restrict__ gates_pk,
    const float* __restrict__ attend_b,
    const float* __restrict__ gru_bih, const float* __restrict__ gru_bhh){
  __shared__ __align__(16) unsigned short Cf[32*512];
  __shared__ __align__(16) unsigned short Bu[2][HALF_U16];
  const int t = threadIdx.x;
  const int w = t>>6, lane = t&63, lr = lane&15, ks = lane>>4;
  const int wm = w>>2, wn = w&3;
  const int m0 = blockIdx.x*64;

  s16x8 pf[6]; int pfn = 0;
  auto LOADS = [&](int s){
    if(s >= 72) return;
    int d2 = s/24, r = s - d2*24;
    const unsigned short* src; int n;
    if(r < 8){ n = 2; src = ctx_pk + ((size_t)d2*8 + r)*8192; }
    else { int g = r - 8; n = 6; src = gates_pk + ((size_t)(d2*2 + (g>>3))*8 + (g&7))*24576; }
    pfn = n;
    #pragma unroll
    for(int c=0;c<6;++c) if(c < n) pf[c] = *(const s16x8*)(src + (w + c*8)*512 + lane*8);
  };
  auto WRITET = [&](int h){
    #pragma unroll
    for(int c=0;c<6;++c) if(c < pfn) *(s16x8*)&Bu[h][(w + c*8)*512 + lane*8] = pf[c];
  };

  LOADS(0);
  WRITET(0);
  LOADS(1);
  int half = 0;

  for(int d=0; d<3; ++d){
    const float* bat  = attend_b + d*256;
    const float* bihd = gru_bih + d*768;
    const float* bhhd = gru_bhh + d*768;

    __syncthreads();      // order prior-radius GRU writes before x preload
    float4 px0[2], px1[2];
    #pragma unroll
    for(int mf=0; mf<2; ++mf){
      int row = m0 + wm*32 + mf*16 + lr;
      const float* sp = (d==0 ? wnf : af) + (size_t)row*256 + ks*8;
      px0[mf] = *(const float4*)sp; px1[mf] = *(const float4*)(sp+4);
    }
    // ---------------- phase 2: ctx (swapped-operand MFMA) ----------------
    f32x4 acc2[2][4] = {};
    for(int kk=0; kk<8; ++kk){
      int s = d*24 + kk;
      __syncthreads();
      WRITET(half^1);
      LOADS(s+2);
      float4 cx0[2] = {px0[0], px0[1]};
      float4 cx1[2] = {px1[0], px1[1]};
      if(kk < 7){
        #pragma unroll
        for(int mf=0; mf<2; ++mf){
          int row = m0 + wm*32 + mf*16 + lr;
          const float* sp = (d==0 ? wnf : af) + (size_t)row*256 + (kk+1)*32 + ks*8;
          px0[mf] = *(const float4*)sp; px1[mf] = *(const float4*)(sp+4);
        }
      }
      s16x8 xf[2];
      #pragma unroll
      for(int mf=0; mf<2; ++mf){
        float4 v0 = cx0[mf], v1 = cx1[mf];
        if(d != 0){
          float sw = swb[m0 + wm*32 + mf*16 + lr];
          v0.x=fmaxf(v0.x,0.f)*sw; v0.y=fmaxf(v0.y,0.f)*sw;
          v0.z=fmaxf(v0.z,0.f)*sw; v0.w=fmaxf(v0.w,0.f)*sw;
          v1.x=fmaxf(v1.x,0.f)*sw; v1.y=fmaxf(v1.y,0.f)*sw;
          v1.z=fmaxf(v1.z,0.f)*sw; v1.w=fmaxf(v1.w,0.f)*sw;
        }
        unsigned short tmp[8] = {f2bf(v0.x),f2bf(v0.y),f2bf(v0.z),f2bf(v0.w),
                                 f2bf(v1.x),f2bf(v1.y),f2bf(v1.z),f2bf(v1.w)};
        xf[mf] = *(s16x8*)tmp;
      }
      #pragma unroll
      for(int nf=0; nf<4; ++nf){
        s16x8 wf = *(const s16x8*)&Bu[half][((wn*4 + nf)*64 + lane)*8];
        acc2[0][nf] = __builtin_amdgcn_mfma_f32_16x16x32_bf16(wf, xf[0], acc2[0][nf],0,0,0);
        acc2[1][nf] = __builtin_amdgcn_mfma_f32_16x16x32_bf16(wf, xf[1], acc2[1][nf],0,0,0);
      }
      half ^= 1;
    }
    // ctx epilogue -> Cf (frag-ordered; verbatim r9)
    #pragma unroll
    for(int mf=0; mf<2; ++mf){
      float swv = swb[m0 + wm*32 + mf*16 + lr];
      #pragma unroll
      for(int nf=0; nf<4; ++nf){
        int nb = wn*64 + nf*16 + ks*4;
        float4 b4 = *(const float4*)&bat[nb];
        float bj[4] = {b4.x, b4.y, b4.z, b4.w};
        unsigned short o4[4];
        #pragma unroll
        for(int j=0;j<4;++j){
          float v = acc2[mf][nf][j] + swv*bj[j];
          v = v > 0.f ? v : expm1f(v);
          o4[j] = f2bf(v);
        }
        int gm = wm*2 + mf;
        int kkp = wn*2 + (nf>>1);
        int lhi = ((nf & 1) << 1) | (ks >> 1);
        int addr = (gm*8 + kkp)*512 + (lhi*16 + lr)*8 + (ks & 1)*4;
        *(uint2*)&Cf[addr] = *(uint2*)o4;
      }
    }
    // ---- preload h frags for (nc=0, kk=0) ----
    float4 ph0[2], ph1[2];
    #pragma unroll
    for(int mf=0; mf<2; ++mf){
      int row = m0 + wm*32 + mf*16 + lr;
      const float* sp = af + (size_t)row*256 + ks*8;
      ph0[mf] = *(const float4*)sp; ph1[mf] = *(const float4*)(sp+4);
    }
    // ---------------- phase 3: gates + GRU (4 acc sets, deferred nc=0 writes) ----------------
    float hnew0[2][2][4];
    for(int nc=0; nc<2; ++nc){
      f32x4 aR[2][2] = {}, aZ[2][2] = {}, aN[2][2] = {}, aH[2][2] = {};
      for(int kk=0; kk<8; ++kk){
        int s = d*24 + 8 + nc*8 + kk;
        __syncthreads();
        if(s < 71) WRITET(half^1);
        LOADS(s+2);
        float4 ch0[2] = {ph0[0], ph0[1]};
        float4 ch1[2] = {ph1[0], ph1[1]};
        bool lastHK = (nc == 1) && (kk == 7);
        if(!lastHK){
          int kkn = (kk < 7) ? kk+1 : 0;
          #pragma unroll
          for(int mf=0; mf<2; ++mf){
            int row = m0 + wm*32 + mf*16 + lr;
            const float* sp = af + (size_t)row*256 + kkn*32 + ks*8;
            ph0[mf] = *(const float4*)sp; ph1[mf] = *(const float4*)(sp+4);
          }
        }
        s16x8 hf[2];
        #pragma unroll
        for(int mf=0; mf<2; ++mf){
          float4 v0 = ch0[mf], v1 = ch1[mf];
          unsigned short tmp[8] = {f2bf(v0.x),f2bf(v0.y),f2bf(v0.z),f2bf(v0.w),
                                   f2bf(v1.x),f2bf(v1.y),f2bf(v1.z),f2bf(v1.w)};
          hf[mf] = *(s16x8*)tmp;
        }
        s16x8 cf0 = *(const s16x8*)&Cf[((wm*2 + 0)*8 + kk)*512 + lane*8];
        s16x8 cf1 = *(const s16x8*)&Cf[((wm*2 + 1)*8 + kk)*512 + lane*8];
        #pragma unroll
        for(int fn=0; fn<2; ++fn){
          int g = wn*2 + fn;
          s16x8 b0 = *(const s16x8*)&Bu[half][((0*8 + g)*64 + lane)*8];
          s16x8 b1 = *(const s16x8*)&Bu[half][((1*8 + g)*64 + lane)*8];
          s16x8 b2 = *(const s16x8*)&Bu[half][((2*8 + g)*64 + lane)*8];
          s16x8 b3 = *(const s16x8*)&Bu[half][((3*8 + g)*64 + lane)*8];
          s16x8 b4 = *(const s16x8*)&Bu[half][((4*8 + g)*64 + lane)*8];
          s16x8 b5 = *(const s16x8*)&Bu[half][((5*8 + g)*64 + lane)*8];
          aR[0][fn] = __builtin_amdgcn_mfma_f32_16x16x32_bf16(cf0, b0, aR[0][fn],0,0,0);
          aR[1][fn] = __builtin_amdgcn_mfma_f32_16x16x32_bf16(cf1, b0, aR[1][fn],0,0,0);
          aZ[0][fn] = __builtin_amdgcn_mfma_f32_16x16x32_bf16(cf0, b1, aZ[0][fn],0,0,0);
          aZ[1][fn] = __builtin_amdgcn_mfma_f32_16x16x32_bf16(cf1, b1, aZ[1][fn],0,0,0);
          aN[0][fn] = __builtin_amdgcn_mfma_f32_16x16x32_bf16(cf0, b2, aN[0][fn],0,0,0);
          aN[1][fn] = __builtin_amdgcn_mfma_f32_16x16x32_bf16(cf1, b2, aN[1][fn],0,0,0);
          aR[0][fn] = __builtin_amdgcn_mfma_f32_16x16x32_bf16(hf[0], b3, aR[0][fn],0,0,0);
          aR[1][fn] = __builtin_amdgcn_mfma_f32_16x16x32_bf16(hf[1], b3, aR[1][fn],0,0,0);
          aZ[0][fn] = __builtin_amdgcn_mfma_f32_16x16x32_bf16(hf[0], b4, aZ[0][fn],0,0,0);
          aZ[1][fn] = __builtin_amdgcn_mfma_f32_16x16x32_bf16(hf[1], b4, aZ[1][fn],0,0,0);
          aH[0][fn] = __builtin_amdgcn_mfma_f32_16x16x32_bf16(hf[0], b5, aH[0][fn],0,0,0);
          aH[1][fn] = __builtin_amdgcn_mfma_f32_16x16x32_bf16(hf[1], b5, aH[1][fn],0,0,0);
        }
        half ^= 1;
      }
      if(nc == 0){
        #pragma unroll
        for(int mf=0; mf<2; ++mf)
          #pragma unroll
          for(int fn=0; fn<2; ++fn){
            int n = wn*32 + fn*16 + lr;
            float brz = bihd[n] + bhhd[n];
            float bzz = bihd[256+n] + bhhd[256+n];
            float bnn = bihd[512+n];
            float bhn = bhhd[512+n];
            #pragma unroll
            for(int j=0;j<4;++j){
              int m = m0 + wm*32 + mf*16 + ks*4 + j;
              float hold = af[(size_t)m*256 + n];
              float r = 1.f/(1.f + expf(-(aR[mf][fn][j] + brz)));
              float z = 1.f/(1.f + expf(-(aZ[mf][fn][j] + bzz)));
              float ng = tanhf(aN[mf][fn][j] + bnn + r*(aH[mf][fn][j] + bhn));
              hnew0[mf][fn][j] = (1.f - z)*ng + z*hold;
            }
          }
      } else {
        #pragma unroll
        for(int mf=0; mf<2; ++mf)
          #pragma unroll
          for(int fn=0; fn<2; ++fn){
            int n = 128 + wn*32 + fn*16 + lr;
            float brz = bihd[n] + bhhd[n];
            float bzz = bihd[256+n] + bhhd[256+n];
            float bnn = bihd[512+n];
            float bhn = bhhd[512+n];
            #pragma unroll
            for(int j=0;j<4;++j){
              int m = m0 + wm*32 + mf*16 + ks*4 + j;
              float hold = af[(size_t)m*256 + n];
              float r = 1.f/(1.f + expf(-(aR[mf][fn][j] + brz)));
              float z = 1.f/(1.f + expf(-(aZ[mf][fn][j] + bzz)));
              float ng = tanhf(aN[mf][fn][j] + bnn + r*(aH[mf][fn][j] + bhn));
              af[(size_t)m*256 + n] = (1.f - z)*ng + z*hold;
            }
          }
        #pragma unroll
        for(int mf=0; mf<2; ++mf)
          #pragma unroll
          for(int fn=0; fn<2; ++fn){
            int n = wn*32 + fn*16 + lr;
            #pragma unroll
            for(int j=0;j<4;++j){
              int m = m0 + wm*32 + mf*16 + ks*4 + j;
              af[(size_t)m*256 + n] = hnew0[mf][fn][j];
            }
          }
      }
    }
  }
}

// ======== K4a — att = X @ W^T + b (f32 out, MFMA) ========
__global__ __launch_bounds__(256) void k_lin_gemm(
    const float* __restrict__ Xsrc, const unsigned short* __restrict__ Wbf,
    const float* __restrict__ bias, float* __restrict__ Y){
  __shared__ unsigned short A_lds[64][264];
  __shared__ unsigned short B_lds[64][264];
  const int t = threadIdx.x;
  const int m0 = (blockIdx.x >> 2) * 64, n0 = (blockIdx.x & 3) * 64;
  const int rb = t >> 4, cb = (t & 15) * 16;
  for(int i=0;i<4;++i){
    int row = i*16 + rb;
    const float* src = Xsrc + (size_t)(m0+row)*FP + cb;
    unsigned short tmp[16];
    #pragma unroll
    for(int q=0;q<4;++q){
      float4 v = ((const float4*)src)[q];
      tmp[q*4+0]=f2bf(v.x); tmp[q*4+1]=f2bf(v.y); tmp[q*4+2]=f2bf(v.z); tmp[q*4+3]=f2bf(v.w);
    }
    *(s16x8*)&A_lds[row][cb]   = *(s16x8*)&tmp[0];
    *(s16x8*)&A_lds[row][cb+8] = *(s16x8*)&tmp[8];
    const unsigned short* wsrc = Wbf + (size_t)(n0+row)*FP + cb;
    *(s16x8*)&B_lds[row][cb]   = *(const s16x8*)&wsrc[0];
    *(s16x8*)&B_lds[row][cb+8] = *(const s16x8*)&wsrc[8];
  }
  __syncthreads();
  const int w = t>>6, lane = t&63, lr = lane&15, ks = lane>>4;
  const int wr = (w>>1)*32, wc = (w&1)*32;
  f32x4 acc[2][2] = {};
  #pragma unroll
  for(int kk=0;kk<8;++kk){
    int ko = kk*32 + ks*8;
    s16x8 a0 = *(const s16x8*)&A_lds[wr+lr][ko];
    s16x8 a1 = *(const s16x8*)&A_lds[wr+16+lr][ko];
    s16x8 b0 = *(const s16x8*)&B_lds[wc+lr][ko];
    s16x8 b1 = *(const s16x8*)&B_lds[wc+16+lr][ko];
    acc[0][0] = __builtin_amdgcn_mfma_f32_16x16x32_bf16(a0,b0,acc[0][0],0,0,0);
    acc[0][1] = __builtin_amdgcn_mfma_f32_16x16x32_bf16(a0,b1,acc[0][1],0,0,0);
    acc[1][0] = __builtin_amdgcn_mfma_f32_16x16x32_bf16(a1,b0,acc[1][0],0,0,0);
    acc[1][1] = __builtin_amdgcn_mfma_f32_16x16x32_bf16(a1,b1,acc[1][1],0,0,0);
  }
  #pragma unroll
  for(int fm=0;fm<2;++fm)
    #pragma unroll
    for(int fn=0;fn<2;++fn){
      int n = n0 + wc + fn*16 + lr;
      float bv = bias[n];
      #pragma unroll
      for(int j=0;j<4;++j){
        int m = m0 + wr + fm*16 + ks*4 + j;
        Y[(size_t)m*FP + n] = acc[fm][fn][j] + bv;
      }
    }
}

// ======== K3b (mol) — 6 gate GEMMs + fused GRU, 32-row tiles ========
__global__ __launch_bounds__(256) void k_gates32(
    const unsigned short* __restrict__ ctxbf, const float* __restrict__ h_glob,
    const unsigned short* __restrict__ wihbf, const unsigned short* __restrict__ whhbf,
    const float* __restrict__ bih, const float* __restrict__ bhh,
    float* __restrict__ h_out){
  __shared__ unsigned short A_ctx[32][40];
  __shared__ unsigned short A_h[32][40];
  __shared__ unsigned short B_lds[6][64][40];
  const int t = threadIdx.x;
  const int m0 = (blockIdx.x >> 2) * 32, nc = (blockIdx.x & 3) * 64;
  const int w = t>>6, lane = t&63, lr = lane&15, ks = lane>>4;
  const int mh = (w>>1)*16, nh = (w&1)*32;
  f32x4 acc[6][2] = {};
  for(int kk=0;kk<8;++kk){
    const int k0 = kk*32;
    __syncthreads();
    {
      int row = t>>3, c4 = (t&7)*4;
      *(uint2*)&A_ctx[row][c4] = *(const uint2*)(ctxbf + (size_t)(m0+row)*FP + k0 + c4);
      float4 hv = *(const float4*)(h_glob + (size_t)(m0+row)*FP + k0 + c4);
      unsigned short ht[4] = {f2bf(hv.x), f2bf(hv.y), f2bf(hv.z), f2bf(hv.w)};
      *(uint2*)&A_h[row][c4] = *(uint2*)ht;
    }
    #pragma unroll
    for(int i=0;i<6;++i){
      int idx = i*256 + t;
      int s = idx >> 8, rem = idx & 255;
      int row = rem >> 2, c8 = (rem & 3)*8;
      const unsigned short* wsrc = (s < 3)
          ? wihbf + (size_t)(s*FP + nc + row)*FP + k0 + c8
          : whhbf + (size_t)((s-3)*FP + nc + row)*FP + k0 + c8;
      *(s16x8*)&B_lds[s][row][c8] = *(const s16x8*)wsrc;
    }
    __syncthreads();
    s16x8 ac = *(const s16x8*)&A_ctx[mh+lr][ks*8];
    s16x8 ah = *(const s16x8*)&A_h[mh+lr][ks*8];
    #pragma unroll
    for(int s=0;s<6;++s){
      s16x8 a = (s < 3) ? ac : ah;
      #pragma unroll
      for(int fn=0;fn<2;++fn){
        s16x8 b = *(const s16x8*)&B_lds[s][nh+fn*16+lr][ks*8];
        acc[s][fn] = __builtin_amdgcn_mfma_f32_16x16x32_bf16(a,b,acc[s][fn],0,0,0);
      }
    }
  }
  #pragma unroll
  for(int fn=0;fn<2;++fn){
    int n = nc + nh + fn*16 + lr;
    float bir = bih[n], biz = bih[FP+n], bin_ = bih[2*FP+n];
    float bhr = bhh[n], bhz = bhh[FP+n], bhn  = bhh[2*FP+n];
    #pragma unroll
    for(int j=0;j<4;++j){
      int m = m0 + mh + ks*4 + j;
      float h = h_glob[(size_t)m*FP + n];
      float ir = acc[0][fn][j]+bir, iz = acc[1][fn][j]+biz, inn = acc[2][fn][j]+bin_;
      float hr = acc[3][fn][j]+bhr, hz = acc[4][fn][j]+bhz, hn  = acc[5][fn][j]+bhn;
      float r = 1.f/(1.f + expf(-(ir+hr)));
      float z = 1.f/(1.f + expf(-(iz+hz)));
      float ng = tanhf(inn + r*hn);
      h_out[(size_t)m*FP + n] = (1.f-z)*ng + z*h;
    }
  }
}

// ======== K4b — molfeat = sum relu(af)*mask; emit out_af ========
__global__ void k_finalize(const float* __restrict__ af, const float* __restrict__ mask,
                           float* __restrict__ molfeat, float* __restrict__ out_af){
  const int b = blockIdx.x, t = threadIdx.x;
  __shared__ float msk_s[NL];
  if(t < NL) msk_s[t] = mask[b*NL + t];
  __syncthreads();
  float mf = 0.f;
  for(int l=0;l<NL;++l){
    float v = af[(size_t)(b*NL + l)*FP + t];
    out_af[(size_t)(b*NL + l)*FP + t] = v;
    mf = fmaf(fmaxf(v,0.f), msk_s[l], mf);
  }
  molfeat[b*FP + t] = mf;
}

// ======== K5a — mol attention -> ctx (bf16) ========
__global__ void k_mol_ctx(const float* __restrict__ af, const float* __restrict__ att,
    const float* __restrict__ mfin, const float* __restrict__ maw,
    const float* __restrict__ mabp, const float* __restrict__ mask,
    unsigned short* __restrict__ ctxb){
  const int b = blockIdx.x, t = threadIdx.x;
  __shared__ float mf_s[FP];
  __shared__ float sc_s[NL], aw_s[NL], scr[4];
  mf_s[t] = mfin[b*FP + t];
  __syncthreads();
  float sa = block_sum256(maw[t]*mf_s[t], scr);
  int l = t >> 2, q = t & 3;
  float p = 0.f;
  {
    const float4* ar = (const float4*)(af + (size_t)(b*NL + l)*FP + q*64);
    const float4* w2 = (const float4*)(maw + FP + q*64);
    #pragma unroll
    for(int k=0;k<16;++k){
      float4 a = ar[k], ww = w2[k];
      p = fmaf(a.x,ww.x,p); p = fmaf(a.y,ww.y,p);
      p = fmaf(a.z,ww.z,p); p = fmaf(a.w,ww.w,p);
    }
  }
  p += __shfl_xor(p, 1, 64);
  p += __shfl_xor(p, 2, 64);
  if(q == 0){
    float mv = mask[b*NL + l];
    float v = sa + p + mabp[0];
    v = v > 0.f ? v : 0.01f*v;
    sc_s[l] = v + (mv == 0.f ? NEGV : 0.f);
  }
  __syncthreads();
  if(t < NL){
    float s = sc_s[t];
    float m = s;
    #pragma unroll
    for(int o=32;o>0;o>>=1) m = fmaxf(m, __shfl_xor(m, o, 64));
    float e = expf(s - m);
    float Z = e;
    #pragma unroll
    for(int o=32;o>0;o>>=1) Z += __shfl_xor(Z, o, 64);
    aw_s[t] = e / Z * mask[b*NL + t];
  }
  __syncthreads();
  float acc = 0.f;
  for(int l2=0;l2<NL;++l2) acc = fmaf(aw_s[l2], att[(size_t)(b*NL + l2)*FP + t], acc);
  float c = acc > 0.f ? acc : expm1f(acc);
  ctxb[b*FP + t] = f2bf(c);
}

// ======== K6: mol_prediction ========
__global__ void k_out(const float* __restrict__ molfeat, const float* __restrict__ ow,
                      const float* __restrict__ ob, float* __restrict__ outp){
  const int b = blockIdx.x, t = threadIdx.x;
  __shared__ float scr[4];
  float s = block_sum256(molfeat[b*FP + t]*ow[t], scr);
  if(t == 0) outp[b] = s + ob[0];
}

extern "C" void kernel_launch(void* const* d_in, const int* in_sizes, int n_in,
                              void* d_out, int out_size, void* d_ws, size_t ws_size,
                              hipStream_t stream){
  const float* atom_list = (const float*)d_in[0];
  const float* bond_list = (const float*)d_in[1];
  const int*   adl       = (const int*)d_in[2];
  const int*   bdl       = (const int*)d_in[3];
  const float* amask     = (const float*)d_in[4];
  const float* afc_w     = (const float*)d_in[5];
  const float* afc_b     = (const float*)d_in[6];
  const float* nfc_w     = (const float*)d_in[7];
  const float* nfc_b     = (const float*)d_in[8];
  const float* align_w   = (const float*)d_in[9];
  const float* align_b   = (const float*)d_in[10];
  const float* attend_w  = (const float*)d_in[11];
  const float* attend_b  = (const float*)d_in[12];
  const float* gru_wih   = (const float*)d_in[13];
  const float* gru_whh   = (const float*)d_in[14];
  const float* gru_bih   = (const float*)d_in[15];
  const float* gru_bhh   = (const float*)d_in[16];
  const float* mol_align_w  = (const float*)d_in[17];
  const float* mol_align_b  = (const float*)d_in[18];
  const float* mol_attend_w = (const float*)d_in[19];
  const float* mol_attend_b = (const float*)d_in[20];
  const float* mg_wih    = (const float*)d_in[21];
  const float* mg_whh    = (const float*)d_in[22];
  const float* mg_bih    = (const float*)d_in[23];
  const float* mg_bhh    = (const float*)d_in[24];
  const float* out_w     = (const float*)d_in[25];
  const float* out_b     = (const float*)d_in[26];

  float* out_af   = (float*)d_out;
  float* out_pred = out_af + (size_t)NB*NL*FP;

  const size_t NROW = (size_t)NB*NL;          // 16384
  const size_t F32_CNT = 2*NROW*FP + NROW + 2*(size_t)NB*FP + 40*256;
  const size_t U16_CNT = (size_t)NB*FP + MCVT_TOT + 52*256 + CTXPK_N + GPK_N;
  const size_t NEED = F32_CNT*4 + U16_CNT*2;

  if(ws_size >= NEED){
    float* af_a    = (float*)d_ws;
    float* wnf     = af_a + NROW*FP;
    float* swb     = wnf  + NROW*FP;
    float* mf_a    = swb  + NROW;
    float* mf_b    = mf_a + (size_t)NB*FP;
    float* afcT    = mf_b + (size_t)NB*FP;
    unsigned short* ctxbf_m = (unsigned short*)(afcT + 40*256);   // mol ctx [NB][FP]
    unsigned short* maw_bf  = ctxbf_m + (size_t)NB*FP;
    unsigned short* mgih_bf = maw_bf + MCVT_N0;
    unsigned short* mghh_bf = mgih_bf + MCVT_N1;
    unsigned short* nfcT_bf = mghh_bf + MCVT_N2;
    unsigned short* ctx_pk  = nfcT_bf + 52*256;
    unsigned short* gates_pk= ctx_pk + CTXPK_N;

    k_cvt_mol<<<(MCVT_TOT+255)/256, 256, 0, stream>>>(mol_attend_w, mg_wih, mg_whh, maw_bf);
    k_pack<<<(CTXPK_N+GPK_N)/256, 256, 0, stream>>>(attend_w, gru_wih, gru_whh, ctx_pk, gates_pk);
    k_tr<<<(40*256 + 52*256)/256, 256, 0, stream>>>(afc_w, nfc_w, afcT, nfcT_bf);

    k_atom4<<<NB*NL/4, 256, 0, stream>>>(atom_list, afcT, afc_b, af_a);
    k_nbr4<<<NB*NL/4, 256, 0, stream>>>(atom_list, bond_list, adl, bdl,
                                        nfcT_bf, nfc_b, align_w, align_b, af_a, wnf, swb);
    k_radius2<<<NB*NL/64, 512, 0, stream>>>(wnf, af_a, swb, ctx_pk, gates_pk,
                                            attend_b, gru_bih, gru_bhh);
    // mol phase
    k_lin_gemm<<<(NB*NL/64)*4, 256, 0, stream>>>(af_a, maw_bf, mol_attend_b, wnf);
    k_finalize<<<NB, 256, 0, stream>>>(af_a, amask, mf_a, out_af);
    float* m_cur = mf_a; float* m_nxt = mf_b;
    for(int s=0; s<2; ++s){
      k_mol_ctx<<<NB, 256, 0, stream>>>(af_a, wnf, m_cur, mol_align_w, mol_align_b,
                                        amask, ctxbf_m);
      k_gates32<<<(NB/32)*4, 256, 0, stream>>>(ctxbf_m, m_cur, mgih_bf, mghh_bf,
                                               mg_bih, mg_bhh, m_nxt);
      float* tmp = m_cur; m_cur = m_nxt; m_nxt = tmp;
    }
    k_out<<<NB, 256, 0, stream>>>(m_cur, out_w, out_b, out_pred);
  } else {
    // safety net (never taken with provided workspace)
    float* af = (float*)d_ws;
    k_atom4<<<NB*NL/4, 256, 0, stream>>>(atom_list, (const float*)afc_w, afc_b, af);
    (void)bond_list; (void)adl; (void)bdl; (void)amask;
    (void)align_w; (void)align_b; (void)attend_w; (void)attend_b;
    (void)gru_wih; (void)gru_whh; (void)gru_bih; (void)gru_bhh;
    (void)mol_align_w; (void)mol_align_b; (void)mol_attend_w; (void)mol_attend_b;
    (void)mg_wih; (void)mg_whh; (void)mg_bih; (void)mg_bhh; (void)out_w; (void)out_b;
  }
}